// Round 3
// baseline (1460.892 us; speedup 1.0000x reference)
//
#include <hip/hip_runtime.h>
#include <cstdint>
#include <cstddef>

// ---------------- problem geometry ----------------
#define H_DIM   2560
#define DINNER  8192
#define GHEADS  32
#define DGATE   4096
#define DH      128
#define BSZ     2
#define LSEQ    4096
#define MROWS   (BSZ*LSEQ)     // 8192 token rows
#define NXP     4224           // precise out width: 4096 x | 32 B | 32 C | 64 pad
#define NCHUNK  64
#define SCHUNK  (LSEQ/NCHUNK)  // 64

typedef __attribute__((ext_vector_type(4))) float  f32x4;
typedef __attribute__((ext_vector_type(8))) __bf16 bf16x8;
typedef unsigned short u16;
typedef unsigned int   u32;

static __device__ __forceinline__ u16 f2bf(float f) {
  union { float f; u32 u; } v; v.f = f;
  u32 r = v.u + 0x7fffu + ((v.u >> 16) & 1u);   // RNE
  return (u16)(r >> 16);
}
static __device__ __forceinline__ float bf2f(u16 u) {
  union { u32 u; float f; } v; v.u = ((u32)u) << 16;
  return v.f;
}
static __device__ __forceinline__ float silu(float x) {
  return x / (1.0f + expf(-x));
}

// ---------------- weight prep ----------------
__global__ void cast_f32_bf16(const float* __restrict__ in, u16* __restrict__ out, int n4) {
  int i = blockIdx.x * blockDim.x + threadIdx.x;
  if (i < n4) {
    f32x4 v = ((const f32x4*)in)[i];
    u32 p0 = (u32)f2bf(v[0]) | ((u32)f2bf(v[1]) << 16);
    u32 p1 = (u32)f2bf(v[2]) | ((u32)f2bf(v[3]) << 16);
    ((uint2*)out)[i] = make_uint2(p0, p1);
  }
}

// wc_hi rows: 0..4095 = Wqkv[0..4095] (x), 4096..8191 = Wqkv[4096..8191] (z),
//             8192..8223 = Wb, 8224..8255 = Wa, 8256..8319 = 0
// wc_lo rows: 0..4095 = lo(Wqkv[0..4095]), 4096..4127 = lo(Wb), 4128..4159 = lo(Wa), 4160..4223 = 0
__global__ void build_wc_split(const float* __restrict__ Wqkv, const float* __restrict__ Wb,
                               const float* __restrict__ Wa, u16* __restrict__ hi,
                               u16* __restrict__ lo) {
  int row = blockIdx.x;              // 0..8319
  const float* src = nullptr;
  if (row < DINNER)            src = Wqkv + (size_t)row * H_DIM;
  else if (row < DINNER + 32)  src = Wb + (size_t)(row - DINNER) * H_DIM;
  else if (row < DINNER + 64)  src = Wa + (size_t)(row - DINNER - 32) * H_DIM;
  const bool has_lo = (row < 4096) || (row >= DINNER);
  u16* oh = hi + (size_t)row * H_DIM;
  u16* ol = has_lo ? (lo + (size_t)(row < 4096 ? row : row - 4096) * H_DIM) : nullptr;
  for (int i = threadIdx.x; i < H_DIM / 4; i += blockDim.x) {
    u16 h[4] = {0, 0, 0, 0}, l[4] = {0, 0, 0, 0};
    if (src) {
      f32x4 v = ((const f32x4*)src)[i];
#pragma unroll
      for (int j = 0; j < 4; j++) {
        h[j] = f2bf(v[j]);
        l[j] = f2bf(v[j] - bf2f(h[j]));
      }
    }
    ((uint2*)oh)[i] = make_uint2((u32)h[0] | ((u32)h[1] << 16), (u32)h[2] | ((u32)h[3] << 16));
    if (ol)
      ((uint2*)ol)[i] = make_uint2((u32)l[0] | ((u32)l[1] << 16), (u32)l[2] | ((u32)l[3] << 16));
  }
}

// ---------------- GEMM helpers ----------------
static __device__ __forceinline__ void gload16(const u16* g, u16* l) {
  __builtin_amdgcn_global_load_lds(
      (const __attribute__((address_space(1))) u32*)g,
      (__attribute__((address_space(3))) u32*)l, 16, 0, 0);
}

// stage 16 f32 -> 16 bf16 (hi) packed as 2x uint4
static __device__ __forceinline__ void cvt16_hi(const float* p, uint4* o) {
  u16 h[16];
#pragma unroll
  for (int q = 0; q < 4; q++) {
    f32x4 v = ((const f32x4*)p)[q];
#pragma unroll
    for (int j = 0; j < 4; j++) h[q * 4 + j] = f2bf(v[j]);
  }
#pragma unroll
  for (int q = 0; q < 2; q++)
    o[q] = make_uint4((u32)h[q*8+0] | ((u32)h[q*8+1] << 16), (u32)h[q*8+2] | ((u32)h[q*8+3] << 16),
                      (u32)h[q*8+4] | ((u32)h[q*8+5] << 16), (u32)h[q*8+6] | ((u32)h[q*8+7] << 16));
}
static __device__ __forceinline__ void cvt16_hilo(const float* p, uint4* oh, uint4* ol) {
  u16 h[16], l[16];
#pragma unroll
  for (int q = 0; q < 4; q++) {
    f32x4 v = ((const f32x4*)p)[q];
#pragma unroll
    for (int j = 0; j < 4; j++) {
      h[q * 4 + j] = f2bf(v[j]);
      l[q * 4 + j] = f2bf(v[j] - bf2f(h[q * 4 + j]));
    }
  }
#pragma unroll
  for (int q = 0; q < 2; q++) {
    oh[q] = make_uint4((u32)h[q*8+0] | ((u32)h[q*8+1] << 16), (u32)h[q*8+2] | ((u32)h[q*8+3] << 16),
                       (u32)h[q*8+4] | ((u32)h[q*8+5] << 16), (u32)h[q*8+6] | ((u32)h[q*8+7] << 16));
    ol[q] = make_uint4((u32)l[q*8+0] | ((u32)l[q*8+1] << 16), (u32)l[q*8+2] | ((u32)l[q*8+3] << 16),
                       (u32)l[q*8+4] | ((u32)l[q*8+5] << 16), (u32)l[q*8+6] | ((u32)l[q*8+7] << 16));
  }
}

// z-GEMM: xzz[m, n] = sum_k hs_f32[m,k] * wc_hi[4096+n, k]; bf16 out. Grid (32, 64), 256 thr.
__global__ __launch_bounds__(256)
void gemm_z(const float* __restrict__ hs, const u16* __restrict__ wc_hi,
            u16* __restrict__ Cout) {
  __shared__ __align__(16) u16 As[128 * 32];
  __shared__ __align__(16) u16 Bs[128 * 32];
  const int tid  = threadIdx.x;
  const int lane = tid & 63;
  const int wave = tid >> 6;
  const int wm = (wave & 1) * 64;
  const int wn = (wave >> 1) * 64;
  const size_t bm = (size_t)blockIdx.y * 128;
  const size_t bn = (size_t)blockIdx.x * 128;

  // A reg-stage coords: 16 elems/thread
  const int ar = tid >> 1;
  const int ac = (tid & 1) * 16;
  const float* ap = hs + (bm + ar) * (size_t)H_DIM + ac;
  uint4* as_dst = (uint4*)&As[ar * 32 + ac];

  // B gload coords
  const int chunk0 = wave * 2, chunk1 = wave * 2 + 1;
  const int e0 = chunk0 * 512 + lane * 8;
  const int e1 = chunk1 * 512 + lane * 8;
  const int r0 = e0 >> 5, c0 = e0 & 31;
  const int r1 = e1 >> 5, c1 = e1 & 31;
  const u16* Bb = wc_hi + (4096 + bn) * (size_t)H_DIM;

  f32x4 acc[4][4];
#pragma unroll
  for (int i = 0; i < 4; i++)
#pragma unroll
    for (int j = 0; j < 4; j++) acc[i][j] = (f32x4){0.f, 0.f, 0.f, 0.f};

  for (int k0 = 0; k0 < H_DIM; k0 += 32) {
    gload16(Bb + (size_t)r0 * H_DIM + k0 + c0, &Bs[chunk0 * 512]);
    gload16(Bb + (size_t)r1 * H_DIM + k0 + c1, &Bs[chunk1 * 512]);
    uint4 ah[2];
    cvt16_hi(ap + k0, ah);
    as_dst[0] = ah[0]; as_dst[1] = ah[1];
    __syncthreads();
    const int fr = lane & 15, fk = (lane >> 4) * 8;
    bf16x8 av[4], bv[4];
#pragma unroll
    for (int i = 0; i < 4; i++) av[i] = *(const bf16x8*)&As[(wm + i * 16 + fr) * 32 + fk];
#pragma unroll
    for (int j = 0; j < 4; j++) bv[j] = *(const bf16x8*)&Bs[(wn + j * 16 + fr) * 32 + fk];
#pragma unroll
    for (int i = 0; i < 4; i++)
#pragma unroll
      for (int j = 0; j < 4; j++)
        acc[i][j] = __builtin_amdgcn_mfma_f32_16x16x32_bf16(av[i], bv[j], acc[i][j], 0, 0, 0);
    __syncthreads();
  }
  const int cr = (lane >> 4) * 4, ccol = lane & 15;
#pragma unroll
  for (int i = 0; i < 4; i++)
#pragma unroll
    for (int j = 0; j < 4; j++)
#pragma unroll
      for (int r = 0; r < 4; r++) {
        size_t row = bm + wm + i * 16 + cr + r;
        size_t col = bn + wn + j * 16 + ccol;
        Cout[row * DGATE + col] = f2bf(acc[i][j][r]);
      }
}

// precise 3-product GEMM for x|B|C: acc += Ah*Bh + Ah*Bl + Al*Bh; f32 out.
// A hi/lo computed in-register from f32 hs. Grid (33, 64), 256 thr.
__global__ __launch_bounds__(256)
void gemm_precise(const float* __restrict__ hs, const u16* __restrict__ wc_hi,
                  const u16* __restrict__ wc_lo, float* __restrict__ Cout) {
  __shared__ __align__(16) u16 Ash[128 * 32];
  __shared__ __align__(16) u16 Asl[128 * 32];
  __shared__ __align__(16) u16 Bsh[128 * 32];
  __shared__ __align__(16) u16 Bsl[128 * 32];
  const int tid  = threadIdx.x;
  const int lane = tid & 63;
  const int wave = tid >> 6;
  const int wm = (wave & 1) * 64;
  const int wn = (wave >> 1) * 64;
  const size_t bm = (size_t)blockIdx.y * 128;
  const int bx = blockIdx.x;
  const size_t wrow_hi = (bx < 32) ? (size_t)bx * 128 : (size_t)DINNER;  // wc_hi row base
  const size_t wrow_lo = (bx < 32) ? (size_t)bx * 128 : (size_t)4096;    // wc_lo row base

  const int ar = tid >> 1;
  const int ac = (tid & 1) * 16;
  const float* ap = hs + (bm + ar) * (size_t)H_DIM + ac;
  uint4* ash_dst = (uint4*)&Ash[ar * 32 + ac];
  uint4* asl_dst = (uint4*)&Asl[ar * 32 + ac];

  const int chunk0 = wave * 2, chunk1 = wave * 2 + 1;
  const int e0 = chunk0 * 512 + lane * 8;
  const int e1 = chunk1 * 512 + lane * 8;
  const int r0 = e0 >> 5, c0 = e0 & 31;
  const int r1 = e1 >> 5, c1 = e1 & 31;
  const u16* Bbh = wc_hi + wrow_hi * (size_t)H_DIM;
  const u16* Bbl = wc_lo + wrow_lo * (size_t)H_DIM;

  f32x4 acc[4][4];
#pragma unroll
  for (int i = 0; i < 4; i++)
#pragma unroll
    for (int j = 0; j < 4; j++) acc[i][j] = (f32x4){0.f, 0.f, 0.f, 0.f};

  for (int k0 = 0; k0 < H_DIM; k0 += 32) {
    gload16(Bbh + (size_t)r0 * H_DIM + k0 + c0, &Bsh[chunk0 * 512]);
    gload16(Bbh + (size_t)r1 * H_DIM + k0 + c1, &Bsh[chunk1 * 512]);
    gload16(Bbl + (size_t)r0 * H_DIM + k0 + c0, &Bsl[chunk0 * 512]);
    gload16(Bbl + (size_t)r1 * H_DIM + k0 + c1, &Bsl[chunk1 * 512]);
    uint4 ah[2], al[2];
    cvt16_hilo(ap + k0, ah, al);
    ash_dst[0] = ah[0]; ash_dst[1] = ah[1];
    asl_dst[0] = al[0]; asl_dst[1] = al[1];
    __syncthreads();
    const int fr = lane & 15, fk = (lane >> 4) * 8;
    bf16x8 avh[4], avl[4], bvh[4], bvl[4];
#pragma unroll
    for (int i = 0; i < 4; i++) {
      avh[i] = *(const bf16x8*)&Ash[(wm + i * 16 + fr) * 32 + fk];
      avl[i] = *(const bf16x8*)&Asl[(wm + i * 16 + fr) * 32 + fk];
    }
#pragma unroll
    for (int j = 0; j < 4; j++) {
      bvh[j] = *(const bf16x8*)&Bsh[(wn + j * 16 + fr) * 32 + fk];
      bvl[j] = *(const bf16x8*)&Bsl[(wn + j * 16 + fr) * 32 + fk];
    }
#pragma unroll
    for (int i = 0; i < 4; i++)
#pragma unroll
      for (int j = 0; j < 4; j++) {
        acc[i][j] = __builtin_amdgcn_mfma_f32_16x16x32_bf16(avh[i], bvh[j], acc[i][j], 0, 0, 0);
        acc[i][j] = __builtin_amdgcn_mfma_f32_16x16x32_bf16(avh[i], bvl[j], acc[i][j], 0, 0, 0);
        acc[i][j] = __builtin_amdgcn_mfma_f32_16x16x32_bf16(avl[i], bvh[j], acc[i][j], 0, 0, 0);
      }
    __syncthreads();
  }
  const int cr = (lane >> 4) * 4, ccol = lane & 15;
#pragma unroll
  for (int i = 0; i < 4; i++)
#pragma unroll
    for (int j = 0; j < 4; j++)
#pragma unroll
      for (int r = 0; r < 4; r++) {
        size_t row = bm + wm + i * 16 + cr + r;
        size_t col = (size_t)bx * 128 + wn + j * 16 + ccol;
        Cout[row * NXP + col] = acc[i][j][r];
      }
}

// plain bf16 GEMM (for GEMM2): C f32 = A bf16 @ Bt bf16. Grid (N/128, M/128).
__global__ __launch_bounds__(256)
void gemm_bt128_f32(const u16* __restrict__ A, const u16* __restrict__ Bt,
                    float* __restrict__ Cout, int K, int ldc) {
  __shared__ __align__(16) u16 As[128 * 32];
  __shared__ __align__(16) u16 Bs[128 * 32];
  const int tid  = threadIdx.x;
  const int lane = tid & 63;
  const int wave = tid >> 6;
  const int wm = (wave & 1) * 64;
  const int wn = (wave >> 1) * 64;
  const size_t bm = (size_t)blockIdx.y * 128;
  const size_t bn = (size_t)blockIdx.x * 128;

  const int chunk0 = wave * 2, chunk1 = wave * 2 + 1;
  const int e0 = chunk0 * 512 + lane * 8;
  const int e1 = chunk1 * 512 + lane * 8;
  const int r0 = e0 >> 5, c0 = e0 & 31;
  const int r1 = e1 >> 5, c1 = e1 & 31;
  const u16* Ab = A + bm * (size_t)K;
  const u16* Bb = Bt + bn * (size_t)K;

  f32x4 acc[4][4];
#pragma unroll
  for (int i = 0; i < 4; i++)
#pragma unroll
    for (int j = 0; j < 4; j++) acc[i][j] = (f32x4){0.f, 0.f, 0.f, 0.f};

  for (int k0 = 0; k0 < K; k0 += 32) {
    gload16(Ab + (size_t)r0 * K + k0 + c0, &As[chunk0 * 512]);
    gload16(Ab + (size_t)r1 * K + k0 + c1, &As[chunk1 * 512]);
    gload16(Bb + (size_t)r0 * K + k0 + c0, &Bs[chunk0 * 512]);
    gload16(Bb + (size_t)r1 * K + k0 + c1, &Bs[chunk1 * 512]);
    __syncthreads();
    const int fr = lane & 15, fk = (lane >> 4) * 8;
    bf16x8 av[4], bv[4];
#pragma unroll
    for (int i = 0; i < 4; i++) av[i] = *(const bf16x8*)&As[(wm + i * 16 + fr) * 32 + fk];
#pragma unroll
    for (int j = 0; j < 4; j++) bv[j] = *(const bf16x8*)&Bs[(wn + j * 16 + fr) * 32 + fk];
#pragma unroll
    for (int i = 0; i < 4; i++)
#pragma unroll
      for (int j = 0; j < 4; j++)
        acc[i][j] = __builtin_amdgcn_mfma_f32_16x16x32_bf16(av[i], bv[j], acc[i][j], 0, 0, 0);
    __syncthreads();
  }
  const int cr = (lane >> 4) * 4, ccol = lane & 15;
#pragma unroll
  for (int i = 0; i < 4; i++)
#pragma unroll
    for (int j = 0; j < 4; j++)
#pragma unroll
      for (int r = 0; r < 4; r++) {
        size_t row = bm + wm + i * 16 + cr + r;
        size_t col = bn + wn + j * 16 + ccol;
        Cout[row * ldc + col] = acc[i][j][r];
      }
}

// ---------------- chunked SSM scan ----------------
// xzx: [M][NXP] f32 (x 0..4095 | B 4096..4127 | C 4128..4159 | pad). xzz: [M][4096] bf16.
__global__ __launch_bounds__(64)
void scan_pass1(const float* __restrict__ xzx, const float* __restrict__ conv_w,
                const float* __restrict__ A_log, const float* __restrict__ dt_bias,
                float* __restrict__ E) {
  const int bid = blockIdx.x;
  const int c   = bid & (NCHUNK - 1);
  const int bg  = bid >> 6;
  const int g   = bg & (GHEADS - 1);
  const int b   = bg >> 5;
  const int lane = threadIdx.x;
  const int ch0 = g * DH + lane, ch1 = ch0 + 64;

  const f32x4 w0 = ((const f32x4*)conv_w)[ch0];
  const f32x4 w1 = ((const f32x4*)conv_w)[ch1];
  const float dt = log1pf(expf(dt_bias[g]));
  const float Ac = -expf(A_log[g]);
  const float dA = expf(dt * Ac);

  const int l0 = c * SCHUNK;
  const float* base = xzx + (size_t)b * LSEQ * NXP;

  float xm3 = 0, xm2 = 0, xm1 = 0, Xm3 = 0, Xm2 = 0, Xm1 = 0;
#pragma unroll
  for (int j = 0; j < 3; j++) {
    int l = l0 - 3 + j;
    float v0 = 0, v1 = 0;
    if (l >= 0) {
      const float* rp = base + (size_t)l * NXP;
      v0 = rp[ch0]; v1 = rp[ch1];
    }
    if (j == 0) { xm3 = v0; Xm3 = v1; }
    else if (j == 1) { xm2 = v0; Xm2 = v1; }
    else { xm1 = v0; Xm1 = v1; }
  }
  float h0 = 0.f, h1 = 0.f;
  for (int t = 0; t < SCHUNK; t++) {
    const float* rp = base + (size_t)(l0 + t) * NXP;
    float xc0 = rp[ch0], xc1 = rp[ch1];
    float cx0 = w0[0] * xm3 + w0[1] * xm2 + w0[2] * xm1 + w0[3] * xc0;
    float cx1 = w1[0] * Xm3 + w1[1] * Xm2 + w1[2] * Xm1 + w1[3] * xc1;
    xm3 = xm2; xm2 = xm1; xm1 = xc0;
    Xm3 = Xm2; Xm2 = Xm1; Xm1 = xc1;
    float u = dt * rp[DGATE + g];
    h0 = dA * h0 + u * silu(cx0);
    h1 = dA * h1 + u * silu(cx1);
  }
  float* ep = E + (size_t)bid * DH;
  ep[lane] = h0; ep[lane + 64] = h1;
}

__global__ __launch_bounds__(64)
void scan_pass2(const float* __restrict__ E, float* __restrict__ Hs,
                const float* __restrict__ A_log, const float* __restrict__ dt_bias) {
  const int bg = blockIdx.x;
  const int g = bg & (GHEADS - 1);
  const int lane = threadIdx.x;
  const float dt = log1pf(expf(dt_bias[g]));
  const float Ac = -expf(A_log[g]);
  const float dAS = expf(dt * Ac * (float)SCHUNK);
  float h0 = 0.f, h1 = 0.f;
  for (int c = 0; c < NCHUNK; c++) {
    size_t idx = ((size_t)bg * NCHUNK + c) * DH;
    Hs[idx + lane] = h0; Hs[idx + lane + 64] = h1;
    h0 = dAS * h0 + E[idx + lane];
    h1 = dAS * h1 + E[idx + lane + 64];
  }
}

__global__ __launch_bounds__(64)
void scan_pass3(const float* __restrict__ xzx, const u16* __restrict__ xzz,
                const float* __restrict__ conv_w,
                const float* __restrict__ A_log, const float* __restrict__ dt_bias,
                const float* __restrict__ norm_w, const float* __restrict__ Hs,
                u16* __restrict__ gbuf) {
  const int bid = blockIdx.x;
  const int c   = bid & (NCHUNK - 1);
  const int bg  = bid >> 6;
  const int g   = bg & (GHEADS - 1);
  const int b   = bg >> 5;
  const int lane = threadIdx.x;
  const int ch0 = g * DH + lane, ch1 = ch0 + 64;

  const f32x4 wx0 = ((const f32x4*)conv_w)[ch0];
  const f32x4 wx1 = ((const f32x4*)conv_w)[ch1];
  const f32x4 wz0 = ((const f32x4*)conv_w)[DGATE + ch0];
  const f32x4 wz1 = ((const f32x4*)conv_w)[DGATE + ch1];
  const float nw0 = norm_w[lane], nw1 = norm_w[lane + 64];

  const float dt = log1pf(expf(dt_bias[g]));
  const float Ac = -expf(A_log[g]);
  const float dA = expf(dt * Ac);

  const int l0 = c * SCHUNK;
  const float* basex = xzx + (size_t)b * LSEQ * NXP;
  const u16*   basez = xzz + (size_t)b * LSEQ * DGATE;

  float xm3 = 0, xm2 = 0, xm1 = 0, Xm3 = 0, Xm2 = 0, Xm1 = 0;
  float zm3 = 0, zm2 = 0, zm1 = 0, Zm3 = 0, Zm2 = 0, Zm1 = 0;
#pragma unroll
  for (int j = 0; j < 3; j++) {
    int l = l0 - 3 + j;
    float vx0 = 0, vx1 = 0, vz0 = 0, vz1 = 0;
    if (l >= 0) {
      const float* rp = basex + (size_t)l * NXP;
      const u16*   rz = basez + (size_t)l * DGATE;
      vx0 = rp[ch0]; vx1 = rp[ch1];
      vz0 = bf2f(rz[ch0]); vz1 = bf2f(rz[ch1]);
    }
    if (j == 0) { xm3 = vx0; Xm3 = vx1; zm3 = vz0; Zm3 = vz1; }
    else if (j == 1) { xm2 = vx0; Xm2 = vx1; zm2 = vz0; Zm2 = vz1; }
    else { xm1 = vx0; Xm1 = vx1; zm1 = vz0; Zm1 = vz1; }
  }
  float h0 = Hs[(size_t)bid * DH + lane];
  float h1 = Hs[(size_t)bid * DH + lane + 64];
  for (int t = 0; t < SCHUNK; t++) {
    const int l = l0 + t;
    const float* rp = basex + (size_t)l * NXP;
    const u16*   rz = basez + (size_t)l * DGATE;
    float xc0 = rp[ch0], xc1 = rp[ch1];
    float zc0 = bf2f(rz[ch0]), zc1 = bf2f(rz[ch1]);
    float cx0 = wx0[0] * xm3 + wx0[1] * xm2 + wx0[2] * xm1 + wx0[3] * xc0;
    float cx1 = wx1[0] * Xm3 + wx1[1] * Xm2 + wx1[2] * Xm1 + wx1[3] * xc1;
    float cz0 = wz0[0] * zm3 + wz0[1] * zm2 + wz0[2] * zm1 + wz0[3] * zc0;
    float cz1 = wz1[0] * Zm3 + wz1[1] * Zm2 + wz1[2] * Zm1 + wz1[3] * zc1;
    xm3 = xm2; xm2 = xm1; xm1 = xc0;  Xm3 = Xm2; Xm2 = Xm1; Xm1 = xc1;
    zm3 = zm2; zm2 = zm1; zm1 = zc0;  Zm3 = Zm2; Zm2 = Zm1; Zm1 = zc1;
    float bcl = rp[DGATE + g];
    float ccl = rp[DGATE + 32 + g];
    float u = dt * bcl;
    h0 = dA * h0 + u * silu(cx0);
    h1 = dA * h1 + u * silu(cx1);
    float y0 = ccl * h0, y1 = ccl * h1;
    float ss = y0 * y0 + y1 * y1;
    ss += __shfl_xor(ss, 32); ss += __shfl_xor(ss, 16); ss += __shfl_xor(ss, 8);
    ss += __shfl_xor(ss, 4);  ss += __shfl_xor(ss, 2);  ss += __shfl_xor(ss, 1);
    const float sc = rsqrtf(ss * (1.0f / DH) + 1e-6f);
    u16* op = gbuf + (size_t)(b * LSEQ + l) * DGATE + g * DH;
    op[lane]      = f2bf(y0 * sc * nw0 * silu(cz0));
    op[lane + 64] = f2bf(y1 * sc * nw1 * silu(cz1));
  }
}

// ---------------- launch ----------------
extern "C" void kernel_launch(void* const* d_in, const int* in_sizes, int n_in,
                              void* d_out, int out_size, void* d_ws, size_t ws_size,
                              hipStream_t stream) {
  (void)in_sizes; (void)n_in; (void)out_size; (void)ws_size;
  const float* hs    = (const float*)d_in[0];
  const float* Wqkv  = (const float*)d_in[1];
  const float* Wb    = (const float*)d_in[2];
  const float* Wa    = (const float*)d_in[3];
  const float* convw = (const float*)d_in[4];
  const float* Wout  = (const float*)d_in[5];
  const float* normw = (const float*)d_in[6];
  const float* Alog  = (const float*)d_in[7];
  const float* dtb   = (const float*)d_in[8];
  float* out = (float*)d_out;

  // ws layout (297 MB total; proven-safe budget is ~313 MB):
  // [xzx 138.4 | xzz 67.1 | wc_hi 42.6 | wc_lo 21.6 | pad 4.2 | wout 21.0 | E 2.1 | Hst 2.1]
  char* ws = (char*)d_ws;
  size_t off = 0;
  auto alloc = [&](size_t bytes) { void* p = ws + off; off += (bytes + 255) & ~(size_t)255; return p; };
  float* xzx    = (float*)alloc((size_t)MROWS * NXP * 4);        // 138.4 MB
  u16*   xzz    = (u16*)alloc((size_t)MROWS * DGATE * 2);        // 67.1 MB
  u16*   wc_hi  = (u16*)alloc((size_t)8320 * H_DIM * 2);         // 42.6 MB
  u16*   wc_lo  = (u16*)alloc((size_t)4224 * H_DIM * 2);         // 21.6 MB
  (void)alloc((size_t)4 << 20);                                  // 4.2 MB pad (gbuf tail)
  u16*   wout_bf= (u16*)alloc((size_t)H_DIM * DGATE * 2);        // 21.0 MB
  float* E      = (float*)alloc((size_t)BSZ * GHEADS * NCHUNK * DH * 4);
  float* Hst    = (float*)alloc((size_t)BSZ * GHEADS * NCHUNK * DH * 4);
  // gbuf (67.1 MB) aliases [wc_hi | wc_lo | pad] (68.4 MB): wc_* are dead after the
  // two GEMM1 kernels; pass3 (the writer) launches strictly after them. Never touches wout.
  u16*   gbuf   = wc_hi;

  build_wc_split<<<8320, 256, 0, stream>>>(Wqkv, Wb, Wa, wc_hi, wc_lo);
  const int n4_wo = H_DIM * DGATE / 4;
  cast_f32_bf16<<<(n4_wo + 255) / 256, 256, 0, stream>>>(Wout, wout_bf, n4_wo);

  // GEMM1a (precise, 3-product): x|B|C -> f32 [8192, 4224]
  gemm_precise<<<dim3(33, MROWS / 128), 256, 0, stream>>>(hs, wc_hi, wc_lo, xzx);
  // GEMM1b (plain): z -> bf16 [8192, 4096]
  gemm_z<<<dim3(32, MROWS / 128), 256, 0, stream>>>(hs, wc_hi, xzz);

  scan_pass1<<<BSZ * GHEADS * NCHUNK, 64, 0, stream>>>(xzx, convw, Alog, dtb, E);
  scan_pass2<<<BSZ * GHEADS, 64, 0, stream>>>(E, Hst, Alog, dtb);
  scan_pass3<<<BSZ * GHEADS * NCHUNK, 64, 0, stream>>>(xzx, xzz, convw, Alog, dtb, normw, Hst, gbuf);

  // GEMM2: out = gated @ W_out^T -> f32 [8192, 2560]
  gemm_bt128_f32<<<dim3(H_DIM / 128, MROWS / 128), 256, 0, stream>>>(gbuf, wout_bf, out, DGATE, H_DIM);
}